// Round 10
// baseline (94.147 us; speedup 1.0000x reference)
//
#include <hip/hip_runtime.h>

// Inverse 2-level orthonormal Haar DWT with zero details ==
// 4x4 nearest-neighbor upsample scaled by 1/4.
// in : [B=128, C=3, 128, 128] f32 (flat)   ( 25 MB)
// out: [B=128, C=3, 512, 512] f32 (flat)   (403 MB, 25,165,824 float4)
//
// R10: the untested matrix cell — fill-kernel mode exactly:
// 2048 blocks x 256 thr (fully co-resident: 524,288 thr = 256 CU x 2048),
// grid-stride over 48 iters, PLAIN stores. The cohort's write window is a
// compact 8 MB monotone sweep -> L2 write-back is clean full-line streaming
// (R7's plain failure had 24576 transient blocks spreading ~100 MB of dirty
// lines; R8's failure was load-latency with too few waves). unroll 8 keeps
// 8 independent loads in flight so the load->store chain never starves the
// store stream. Store instr = 64 lanes x 16 B = 1 KB contiguous.

typedef float f32x4 __attribute__((ext_vector_type(4)));

#define NTHREADS (2048 * 256)   // 524,288
#define ITERS    48             // 25,165,824 / 524,288 (exact)

__global__ void __launch_bounds__(256) haar_upsample4_kernel(
        const float* __restrict__ z, float* __restrict__ out) {
    const int tid = blockIdx.x * 256 + threadIdx.x;
    f32x4* o4 = reinterpret_cast<f32x4*>(out);

    // i = tid + it*NTHREADS ; NTHREADS % (128*512) == 0 so w4 and h are
    // loop-invariant; only bc advances (+8 per iter).
    const int w4   = tid & 127;
    const int r0   = tid >> 7;
    const int h    = r0 & 511;
    const int h_in = h >> 2;
    const int bc0  = r0 >> 9;                 // 0..7
    const int zoff = (h_in << 7) + w4;

    #pragma unroll 8
    for (int it = 0; it < ITERS; ++it) {
        const int bc  = bc0 + (it << 3);      // +8 per iter
        const float v = z[(bc << 14) + zoff] * 0.25f;
        const f32x4 o = {v, v, v, v};
        o4[tid + (size_t)it * NTHREADS] = o;  // plain store, monotone window
    }
}

extern "C" void kernel_launch(void* const* d_in, const int* in_sizes, int n_in,
                              void* d_out, int out_size, void* d_ws, size_t ws_size,
                              hipStream_t stream) {
    const float* z = (const float*)d_in[0];
    float* out = (float*)d_out;
    haar_upsample4_kernel<<<2048, 256, 0, stream>>>(z, out);
}

// Round 11
// 70.191 us; speedup vs baseline: 1.3413x; 1.3413x over previous
//
#include <hip/hip_runtime.h>

// Inverse 2-level orthonormal Haar DWT with zero details ==
// 4x4 nearest-neighbor upsample scaled by 1/4.
// in : [B=128, C=3, 128, 128] f32 (flat)   ( 25 MB)
// out: [B=128, C=3, 512, 512] f32 (flat)   (403 MB)
//
// BEST MEASURED (R6 = 70.4 us, 6.08 TB/s effective = 97% of the 6.29 TB/s
// copy ceiling). Restored verbatim after R7-R10 exploration all regressed.
// Why this shape wins (R4..R10 evidence):
//  - per-INSTRUCTION wave footprint 1 KB contiguous (R4: strided-per-lane
//    stores -> 2.1x write amplification, 317 us).
//  - high occupancy, small per-wave store span (R8 persistent / R10 deep
//    unroll spread the span -> 94-98 us).
//  - nt stores beat plain in steady state (R5 75.2 vs R7 82.8).
//  - final >L2-sized PLAIN region (2nd dispatch, 201 MB): its last ~32 MB
//    retire dirty in L2 and flush overlapped with the next replay's ramp
//    (deferred-flush pipelining). Same-address 32 MB plain tail inside one
//    dispatch does NOT work (R9, 87.2 us).

typedef float f32x4 __attribute__((ext_vector_type(4)));

template <bool NT>
__global__ void __launch_bounds__(256) haar_upsample4_kernel(
        const float* __restrict__ z, float* __restrict__ out, int block_base) {
    const int t    = threadIdx.x;
    const int blk  = blockIdx.x + block_base;
    const int base = blk << 10;               // 1024 float4s per block
    const int w4   = t & 127;                 // input pixel column
    const int r0   = (base >> 7) + (t >> 7);  // j>>7 for k=0

    float v[4];
    #pragma unroll
    for (int k = 0; k < 4; ++k) {
        // j = base + k*256 + t ; rest = j>>7 = r0 + 2k ; w4 = j&127 = t&127
        const int rest = r0 + (k << 1);
        const int h    = rest & 511;          // output row
        const int bc   = rest >> 9;           // b*C + c, < 384
        const int h_in = h >> 2;
        v[k] = z[(bc << 14) + (h_in << 7) + w4] * 0.25f;
    }

    f32x4* o = reinterpret_cast<f32x4*>(out) + base + t;
    #pragma unroll
    for (int k = 0; k < 4; ++k) {
        const f32x4 o4 = {v[k], v[k], v[k], v[k]};
        if constexpr (NT) {
            __builtin_nontemporal_store(o4, o + (k << 8));
        } else {
            o[k << 8] = o4;
        }
    }
}

extern "C" void kernel_launch(void* const* d_in, const int* in_sizes, int n_in,
                              void* d_out, int out_size, void* d_ws, size_t ws_size,
                              hipStream_t stream) {
    const float* z = (const float*)d_in[0];
    float* out = (float*)d_out;
    const int total4 = out_size >> 2;        // 25,165,824 float4s
    const int grid   = total4 >> 10;         // 8192 blocks total
    const int half   = grid >> 1;            // 4096 per variant

    haar_upsample4_kernel<true ><<<half, 256, 0, stream>>>(z, out, 0);
    haar_upsample4_kernel<false><<<half, 256, 0, stream>>>(z, out, half);
}